// Round 2
// baseline (2195.031 us; speedup 1.0000x reference)
//
#include <hip/hip_runtime.h>

#define BM    64     // edges (rows) per block
#define PAD_A 132    // LDS row stride for A/M tile (floats)
#define PAD_W 132    // LDS row stride for W1T slab (floats)
#define PAD_S 68     // LDS row stride for WsT slab (floats)

// ---------------------------------------------------------------------------
// Pre-transpose weights into ws so all LDS staging is coalesced.
// W1T[k][c] = W1[c][k]   (128x128)
// WsT[k][d] = Ws[d][k]   (128x64)
// WhT[k][c] = Wh[c][k]   (128x128)
// ---------------------------------------------------------------------------
__global__ __launch_bounds__(256) void transpose_weights(
    const float* __restrict__ W1, const float* __restrict__ Ws,
    const float* __restrict__ Wh,
    float* __restrict__ W1T, float* __restrict__ WsT, float* __restrict__ WhT)
{
    int i = blockIdx.x * 256 + threadIdx.x;
    if (i < 128 * 128) {
        int k = i >> 7, c = i & 127;
        W1T[i] = W1[c * 128 + k];
        WhT[i] = Wh[c * 128 + k];
    }
    if (i < 128 * 64) {
        int k = i >> 6, d = i & 63;
        WsT[i] = Ws[d * 128 + k];
    }
}

// ---------------------------------------------------------------------------
// Fused edge kernel: gather+sum -> message GEMM -> attn GEMM -> alpha ->
// scale -> atomic scatter into agg. 64 edges per block, 256 threads.
// Barrier schedule: 2 per W1T slab (x2 slabs) + 1 before phase 2 = 5 total.
// ---------------------------------------------------------------------------
__global__ __launch_bounds__(256, 2) void edge_kernel(
    const float* __restrict__ hidden,
    const int*   __restrict__ edges,
    const float* __restrict__ h_sub,
    const float* __restrict__ rela,
    const float* __restrict__ W1T,
    const float* __restrict__ WsT,
    const float* __restrict__ w_alpha,
    const float* __restrict__ w_alpha_b,
    float* __restrict__ agg,
    float* __restrict__ alpha_out,
    int E)
{
    __shared__ float A_s[BM * PAD_A];   // 33.8 KB: A tile, then message tile
    __shared__ float W_s[128 * PAD_S];  // 34.8 KB: W1T 64-row slab / full WsT
    __shared__ int   obj_s[BM];

    const int t  = threadIdx.x;
    const int e0 = blockIdx.x * BM;

    // ---- stage A = hidden[sub] + rela[rel] + h_sub  (4 threads per edge) ----
    {
        const int e_loc = t >> 2;        // 0..63
        const int seg   = t & 3;         // 32 floats each
        const int e     = e0 + e_loc;
        float4* dst = (float4*)(A_s + e_loc * PAD_A + seg * 32);
        if (e < E) {
            const int sub = edges[e * 6 + 4];
            const int rel = edges[e * 6 + 2];
            if (seg == 0) obj_s[e_loc] = edges[e * 6 + 5];
            const float4* hs = (const float4*)(hidden + (size_t)sub * 128 + seg * 32);
            const float4* hr = (const float4*)(rela   + (size_t)rel * 128 + seg * 32);
            const float4* hb = (const float4*)(h_sub  + (size_t)e   * 128 + seg * 32);
#pragma unroll
            for (int q = 0; q < 8; ++q) {
                float4 a = hs[q], b = hr[q], c = hb[q];
                dst[q] = make_float4(a.x + b.x + c.x, a.y + b.y + c.y,
                                     a.z + b.z + c.z, a.w + b.w + c.w);
            }
        } else {
            if (seg == 0) obj_s[e_loc] = 0;
            float4 z = make_float4(0.f, 0.f, 0.f, 0.f);
#pragma unroll
            for (int q = 0; q < 8; ++q) dst[q] = z;
        }
    }
    __syncthreads();

    const int tr = t >> 4;   // 0..15 -> rows 4*tr..4*tr+3
    const int tc = t & 15;   // 0..15 -> cols 8*tc..8*tc+7 (phase 1)

    // ---- phase 1: message = A @ W1^T, register tile 4x8, BK=64 ----
    float acc[4][8];
#pragma unroll
    for (int i = 0; i < 4; ++i)
#pragma unroll
        for (int j = 0; j < 8; ++j) acc[i][j] = 0.f;

    for (int kk = 0; kk < 2; ++kk) {
        {   // stage W1T slab rows kk*64..+63 (128 cols) -> W_s[r][c], pad 132
            const int r  = t >> 2;          // 0..63
            const int c0 = (t & 3) * 32;    // 32 floats = 8 float4
            const float4* src = (const float4*)(W1T + (size_t)(kk * 64 + r) * 128 + c0);
            float4* dst = (float4*)(W_s + r * PAD_W + c0);
#pragma unroll
            for (int q = 0; q < 8; ++q) dst[q] = src[q];
        }
        __syncthreads();
#pragma unroll
        for (int k4 = 0; k4 < 16; ++k4) {
            float a[4][4];
#pragma unroll
            for (int i = 0; i < 4; ++i) {
                float4 v = *(const float4*)(A_s + (4 * tr + i) * PAD_A + kk * 64 + k4 * 4);
                a[i][0] = v.x; a[i][1] = v.y; a[i][2] = v.z; a[i][3] = v.w;
            }
            float4 b0[4], b1[4];
#pragma unroll
            for (int k = 0; k < 4; ++k) {
                const float* wrow = W_s + (k4 * 4 + k) * PAD_W + 8 * tc;
                b0[k] = *(const float4*)(wrow);
                b1[k] = *(const float4*)(wrow + 4);
            }
#pragma unroll
            for (int i = 0; i < 4; ++i)
#pragma unroll
                for (int k = 0; k < 4; ++k) {
                    const float av = a[i][k];
                    acc[i][0] = fmaf(av, b0[k].x, acc[i][0]);
                    acc[i][1] = fmaf(av, b0[k].y, acc[i][1]);
                    acc[i][2] = fmaf(av, b0[k].z, acc[i][2]);
                    acc[i][3] = fmaf(av, b0[k].w, acc[i][3]);
                    acc[i][4] = fmaf(av, b1[k].x, acc[i][4]);
                    acc[i][5] = fmaf(av, b1[k].y, acc[i][5]);
                    acc[i][6] = fmaf(av, b1[k].z, acc[i][6]);
                    acc[i][7] = fmaf(av, b1[k].w, acc[i][7]);
                }
        }
        __syncthreads();
    }

    // ---- write message tile into LDS (reuse A_s) + stage full WsT ----
#pragma unroll
    for (int i = 0; i < 4; ++i) {
        float4* dst = (float4*)(A_s + (4 * tr + i) * PAD_A + 8 * tc);
        dst[0] = make_float4(acc[i][0], acc[i][1], acc[i][2], acc[i][3]);
        dst[1] = make_float4(acc[i][4], acc[i][5], acc[i][6], acc[i][7]);
    }
    {   // stage WsT rows 0..127 (64 cols) -> W_s[k][d], pad 68
        const int r  = t >> 1;          // 0..127
        const int c0 = (t & 1) * 32;    // 32 floats = 8 float4
        const float4* src = (const float4*)(WsT + (size_t)r * 64 + c0);
        float4* dst = (float4*)(W_s + r * PAD_S + c0);
#pragma unroll
        for (int q = 0; q < 8; ++q) dst[q] = src[q];
    }
    __syncthreads();

    // ---- phase 2: attn_h = M @ Ws^T, register tile 4x4, no barriers ----
    float acc2[4][4];
#pragma unroll
    for (int i = 0; i < 4; ++i)
#pragma unroll
        for (int j = 0; j < 4; ++j) acc2[i][j] = 0.f;

#pragma unroll
    for (int k4 = 0; k4 < 32; ++k4) {
        float m[4][4];
#pragma unroll
        for (int i = 0; i < 4; ++i) {
            float4 v = *(const float4*)(A_s + (4 * tr + i) * PAD_A + k4 * 4);
            m[i][0] = v.x; m[i][1] = v.y; m[i][2] = v.z; m[i][3] = v.w;
        }
        float4 w[4];
#pragma unroll
        for (int k = 0; k < 4; ++k)
            w[k] = *(const float4*)(W_s + (k4 * 4 + k) * PAD_S + 4 * tc);
#pragma unroll
        for (int i = 0; i < 4; ++i)
#pragma unroll
            for (int k = 0; k < 4; ++k) {
                const float mv = m[i][k];
                acc2[i][0] = fmaf(mv, w[k].x, acc2[i][0]);
                acc2[i][1] = fmaf(mv, w[k].y, acc2[i][1]);
                acc2[i][2] = fmaf(mv, w[k].z, acc2[i][2]);
                acc2[i][3] = fmaf(mv, w[k].w, acc2[i][3]);
            }
    }

    // ---- alpha = sigmoid( sum_d w_alpha[d]*relu(attn_h[d]) + b ) ----
    const float4 wa   = *(const float4*)(w_alpha + 4 * tc);
    const float  bias = w_alpha_b[0];
    float al[4];
#pragma unroll
    for (int i = 0; i < 4; ++i) {
        float p = fmaxf(acc2[i][0], 0.f) * wa.x + fmaxf(acc2[i][1], 0.f) * wa.y
                + fmaxf(acc2[i][2], 0.f) * wa.z + fmaxf(acc2[i][3], 0.f) * wa.w;
#pragma unroll
        for (int off = 1; off < 16; off <<= 1)
            p += __shfl_xor(p, off, 64);          // reduce over the 16 tc lanes
        al[i] = 1.f / (1.f + __expf(-(p + bias)));
    }
    if (tc == 0) {
#pragma unroll
        for (int i = 0; i < 4; ++i) {
            const int e = e0 + 4 * tr + i;
            if (e < E) alpha_out[e] = al[i];
        }
    }

    // ---- scale message by alpha, HW fp32 atomic scatter-add into agg ----
#pragma unroll
    for (int i = 0; i < 4; ++i) {
        const int e = e0 + 4 * tr + i;
        if (e >= E) continue;
        const float a = al[i];
        float* dst = agg + (size_t)obj_s[4 * tr + i] * 128 + 8 * tc;
#pragma unroll
        for (int j = 0; j < 8; ++j)
            unsafeAtomicAdd(dst + j, a * acc[i][j]);   // global_atomic_add_f32
    }
}

// ---------------------------------------------------------------------------
// hidden_new = agg @ W_h^T   (register-tiled GEMM over node rows, BK=64)
// ---------------------------------------------------------------------------
__global__ __launch_bounds__(256, 2) void out_gemm(
    const float* __restrict__ agg, const float* __restrict__ WhT,
    float* __restrict__ out, int N)
{
    __shared__ float A_s[BM * PAD_A];
    __shared__ float W_s[64 * PAD_W];

    const int t  = threadIdx.x;
    const int n0 = blockIdx.x * BM;

    {   // stage A rows from agg
        const int r_loc = t >> 2;
        const int seg   = t & 3;
        const int n     = n0 + r_loc;
        float4* dst = (float4*)(A_s + r_loc * PAD_A + seg * 32);
        if (n < N) {
            const float4* src = (const float4*)(agg + (size_t)n * 128 + seg * 32);
#pragma unroll
            for (int q = 0; q < 8; ++q) dst[q] = src[q];
        } else {
            float4 z = make_float4(0.f, 0.f, 0.f, 0.f);
#pragma unroll
            for (int q = 0; q < 8; ++q) dst[q] = z;
        }
    }
    __syncthreads();

    const int tr = t >> 4;
    const int tc = t & 15;

    float acc[4][8];
#pragma unroll
    for (int i = 0; i < 4; ++i)
#pragma unroll
        for (int j = 0; j < 8; ++j) acc[i][j] = 0.f;

    for (int kk = 0; kk < 2; ++kk) {
        {
            const int r  = t >> 2;
            const int c0 = (t & 3) * 32;
            const float4* src = (const float4*)(WhT + (size_t)(kk * 64 + r) * 128 + c0);
            float4* dst = (float4*)(W_s + r * PAD_W + c0);
#pragma unroll
            for (int q = 0; q < 8; ++q) dst[q] = src[q];
        }
        __syncthreads();
#pragma unroll
        for (int k4 = 0; k4 < 16; ++k4) {
            float a[4][4];
#pragma unroll
            for (int i = 0; i < 4; ++i) {
                float4 v = *(const float4*)(A_s + (4 * tr + i) * PAD_A + kk * 64 + k4 * 4);
                a[i][0] = v.x; a[i][1] = v.y; a[i][2] = v.z; a[i][3] = v.w;
            }
            float4 b0[4], b1[4];
#pragma unroll
            for (int k = 0; k < 4; ++k) {
                const float* wrow = W_s + (k4 * 4 + k) * PAD_W + 8 * tc;
                b0[k] = *(const float4*)(wrow);
                b1[k] = *(const float4*)(wrow + 4);
            }
#pragma unroll
            for (int i = 0; i < 4; ++i)
#pragma unroll
                for (int k = 0; k < 4; ++k) {
                    const float av = a[i][k];
                    acc[i][0] = fmaf(av, b0[k].x, acc[i][0]);
                    acc[i][1] = fmaf(av, b0[k].y, acc[i][1]);
                    acc[i][2] = fmaf(av, b0[k].z, acc[i][2]);
                    acc[i][3] = fmaf(av, b0[k].w, acc[i][3]);
                    acc[i][4] = fmaf(av, b1[k].x, acc[i][4]);
                    acc[i][5] = fmaf(av, b1[k].y, acc[i][5]);
                    acc[i][6] = fmaf(av, b1[k].z, acc[i][6]);
                    acc[i][7] = fmaf(av, b1[k].w, acc[i][7]);
                }
        }
        __syncthreads();
    }

#pragma unroll
    for (int i = 0; i < 4; ++i) {
        const int n = n0 + 4 * tr + i;
        if (n >= N) continue;
        float4* dst = (float4*)(out + (size_t)n * 128 + 8 * tc);
        dst[0] = make_float4(acc[i][0], acc[i][1], acc[i][2], acc[i][3]);
        dst[1] = make_float4(acc[i][4], acc[i][5], acc[i][6], acc[i][7]);
    }
}

// ---------------------------------------------------------------------------
extern "C" void kernel_launch(void* const* d_in, const int* in_sizes, int n_in,
                              void* d_out, int out_size, void* d_ws, size_t ws_size,
                              hipStream_t stream)
{
    // inputs (setup_inputs order):
    // 0 q_sub(int,8) 1 hidden(f32,N*128) 2 edges(int,E*6) 3 n_node(int,1)
    // 4 old_nodes_new_idx 5 entity_pretrain_emb 6 h_sub(f32,E*128)
    // 7 rela_embed(f32,200*128) 8 W1(128*128) 9 Ws_attn(64*128) 10 Wr_attn
    // 11 w_alpha_w(1*64) 12 w_alpha_b(1) 13 W_h(128*128)
    const float* hidden   = (const float*)d_in[1];
    const int*   edges    = (const int*)  d_in[2];
    const float* h_sub    = (const float*)d_in[6];
    const float* rela     = (const float*)d_in[7];
    const float* W1       = (const float*)d_in[8];
    const float* Ws       = (const float*)d_in[9];
    const float* w_alpha  = (const float*)d_in[11];
    const float* w_alphab = (const float*)d_in[12];
    const float* Wh       = (const float*)d_in[13];

    const int N = in_sizes[1] / 128;
    const int E = in_sizes[2] / 6;

    // ws layout
    float* agg = (float*)d_ws;                       // N*128
    float* W1T = agg + (size_t)N * 128;              // 128*128
    float* WsT = W1T + 128 * 128;                    // 128*64
    float* WhT = WsT + 128 * 64;                     // 128*128

    float* out_hidden = (float*)d_out;               // N*128
    float* out_alpha  = out_hidden + (size_t)N * 128;// E

    hipMemsetAsync(agg, 0, (size_t)N * 128 * sizeof(float), stream);
    transpose_weights<<<64, 256, 0, stream>>>(W1, Ws, Wh, W1T, WsT, WhT);

    edge_kernel<<<(E + BM - 1) / BM, 256, 0, stream>>>(
        hidden, edges, h_sub, rela, W1T, WsT, w_alpha, w_alphab,
        agg, out_alpha, E);

    out_gemm<<<(N + BM - 1) / BM, 256, 0, stream>>>(agg, WhT, out_hidden, N);
}

// Round 3
// 809.431 us; speedup vs baseline: 2.7118x; 2.7118x over previous
//
#include <hip/hip_runtime.h>

#define BM    64
#define PAD_A 132    // LDS row stride for A tile (floats)
#define PAD_W 132    // LDS row stride for WcT slab (floats)
#define PAD_S 68     // LDS row stride for WscT slab (floats)

// ---------------------------------------------------------------------------
// Fold weights:
//   WscT[c][d] = (Ws_attn @ W1)[d][c] = sum_k Ws[d*128+k] * W1[k*128+c]   (128x64)
//   WcT [c][o] = (W_h    @ W1)[o][c] = sum_m Wh[o*128+m] * W1[m*128+c]   (128x128)
// Lanes vary over c -> W1 reads coalesced, Ws/Wh reads wave-uniform.
// ---------------------------------------------------------------------------
__global__ __launch_bounds__(256) void fold_weights(
    const float* __restrict__ W1, const float* __restrict__ Ws,
    const float* __restrict__ Wh,
    float* __restrict__ WscT, float* __restrict__ WcT)
{
    int i = blockIdx.x * 256 + threadIdx.x;
    if (i < 128 * 64) {                 // WscT
        int c = i & 127, d = i >> 7;
        float acc = 0.f;
        for (int k = 0; k < 128; ++k)
            acc = fmaf(Ws[d * 128 + k], W1[k * 128 + c], acc);
        WscT[c * 64 + d] = acc;
    } else if (i < 128 * 64 + 128 * 128) {   // WcT
        int j = i - 128 * 64;
        int c = j & 127, o = j >> 7;
        float acc = 0.f;
        for (int m = 0; m < 128; ++m)
            acc = fmaf(Wh[o * 128 + m], W1[m * 128 + c], acc);
        WcT[c * 128 + o] = acc;
    }
}

// ---------------------------------------------------------------------------
// CSR build: histogram -> 2-level exclusive scan -> fill
// ---------------------------------------------------------------------------
__global__ __launch_bounds__(256) void hist_kernel(
    const int* __restrict__ edges, int* __restrict__ deg, int E)
{
    int e = blockIdx.x * 256 + threadIdx.x;
    if (e < E) atomicAdd(&deg[edges[e * 6 + 5]], 1);
}

__global__ __launch_bounds__(256) void scan1_kernel(
    const int* __restrict__ deg, int* __restrict__ incl,
    int* __restrict__ sums, int N)
{
    __shared__ int s[256];
    const int t = threadIdx.x;
    const int g = blockIdx.x * 256 + t;
    int v = (g < N) ? deg[g] : 0;
    s[t] = v; __syncthreads();
    for (int off = 1; off < 256; off <<= 1) {
        int x = (t >= off) ? s[t - off] : 0;
        __syncthreads();
        s[t] += x;
        __syncthreads();
    }
    if (g < N) incl[g] = s[t];
    if (t == 255) sums[blockIdx.x] = s[255];
}

__global__ __launch_bounds__(512) void scan2_kernel(
    const int* __restrict__ sums, int* __restrict__ offs, int NB)
{
    __shared__ int s[512];
    const int t = threadIdx.x;
    int v = (t < NB) ? sums[t] : 0;
    s[t] = v; __syncthreads();
    for (int off = 1; off < 512; off <<= 1) {
        int x = (t >= off) ? s[t - off] : 0;
        __syncthreads();
        s[t] += x;
        __syncthreads();
    }
    if (t < NB) offs[t] = s[t] - v;        // exclusive
}

__global__ __launch_bounds__(256) void scan3_kernel(
    const int* __restrict__ incl, const int* __restrict__ deg,
    const int* __restrict__ offs,
    int* __restrict__ start, int* __restrict__ cursor, int N)
{
    int g = blockIdx.x * 256 + threadIdx.x;
    if (g < N) {
        int st = incl[g] - deg[g] + offs[g >> 8];   // exclusive prefix
        start[g]  = st;
        cursor[g] = st;
    }
}

__global__ __launch_bounds__(256) void fill_kernel(
    const int* __restrict__ edges, int* __restrict__ cursor,
    int* __restrict__ idx, int E)
{
    int e = blockIdx.x * 256 + threadIdx.x;
    if (e < E) {
        int pos = atomicAdd(&cursor[edges[e * 6 + 5]], 1);
        idx[pos] = e;
    }
}

// ---------------------------------------------------------------------------
// Edge kernel: gather A = hidden[sub]+rela[rel]+h_sub, attn GEMM with folded
// WscT, alpha = sigmoid(wa . relu(attn) + b). Writes ONLY alpha. No atomics.
// LDS = 33.8K (A) + 17.4K (Wsc slab) = 51.2 KB -> 3 blocks/CU.
// ---------------------------------------------------------------------------
__global__ __launch_bounds__(256, 3) void edge_alpha_kernel(
    const float* __restrict__ hidden,
    const int*   __restrict__ edges,
    const float* __restrict__ h_sub,
    const float* __restrict__ rela,
    const float* __restrict__ WscT,
    const float* __restrict__ w_alpha,
    const float* __restrict__ w_alpha_b,
    float* __restrict__ alpha_out,
    int E)
{
    __shared__ float A_s[BM * PAD_A];     // 33792 B
    __shared__ float W_s[64 * PAD_S];     // 17408 B

    const int t  = threadIdx.x;
    const int e0 = blockIdx.x * BM;

    // ---- stage A (4 threads per edge, 32 floats each) ----
    {
        const int e_loc = t >> 2;
        const int seg   = t & 3;
        const int e     = e0 + e_loc;
        float4* dst = (float4*)(A_s + e_loc * PAD_A + seg * 32);
        if (e < E) {
            const int sub = edges[e * 6 + 4];
            const int rel = edges[e * 6 + 2];
            const float4* hs = (const float4*)(hidden + (size_t)sub * 128 + seg * 32);
            const float4* hr = (const float4*)(rela   + (size_t)rel * 128 + seg * 32);
            const float4* hb = (const float4*)(h_sub  + (size_t)e   * 128 + seg * 32);
#pragma unroll
            for (int q = 0; q < 8; ++q) {
                float4 a = hs[q], b = hr[q], c = hb[q];
                dst[q] = make_float4(a.x + b.x + c.x, a.y + b.y + c.y,
                                     a.z + b.z + c.z, a.w + b.w + c.w);
            }
        } else {
            float4 z = make_float4(0.f, 0.f, 0.f, 0.f);
#pragma unroll
            for (int q = 0; q < 8; ++q) dst[q] = z;
        }
    }
    __syncthreads();

    const int tr = t >> 4;   // 0..15 -> rows 4*tr..4*tr+3
    const int tc = t & 15;   // 0..15 -> attn cols 4*tc..4*tc+3

    // ---- attn = A @ Wsc^T, register tile 4x4, two 64-row slabs of WscT ----
    float acc2[4][4];
#pragma unroll
    for (int i = 0; i < 4; ++i)
#pragma unroll
        for (int j = 0; j < 4; ++j) acc2[i][j] = 0.f;

    for (int kk = 0; kk < 2; ++kk) {
        {   // stage WscT rows kk*64..+63 (64 cols) -> W_s, pad 68
            const int r  = t >> 2;          // 0..63
            const int c0 = (t & 3) * 16;    // 4 float4
            const float4* src = (const float4*)(WscT + (size_t)(kk * 64 + r) * 64 + c0);
            float4* dst = (float4*)(W_s + r * PAD_S + c0);
#pragma unroll
            for (int q = 0; q < 4; ++q) dst[q] = src[q];
        }
        __syncthreads();
#pragma unroll
        for (int k4 = 0; k4 < 16; ++k4) {
            float m[4][4];
#pragma unroll
            for (int i = 0; i < 4; ++i) {
                float4 v = *(const float4*)(A_s + (4 * tr + i) * PAD_A + kk * 64 + k4 * 4);
                m[i][0] = v.x; m[i][1] = v.y; m[i][2] = v.z; m[i][3] = v.w;
            }
            float4 w[4];
#pragma unroll
            for (int k = 0; k < 4; ++k)
                w[k] = *(const float4*)(W_s + (k4 * 4 + k) * PAD_S + 4 * tc);
#pragma unroll
            for (int i = 0; i < 4; ++i)
#pragma unroll
                for (int k = 0; k < 4; ++k) {
                    const float mv = m[i][k];
                    acc2[i][0] = fmaf(mv, w[k].x, acc2[i][0]);
                    acc2[i][1] = fmaf(mv, w[k].y, acc2[i][1]);
                    acc2[i][2] = fmaf(mv, w[k].z, acc2[i][2]);
                    acc2[i][3] = fmaf(mv, w[k].w, acc2[i][3]);
                }
        }
        __syncthreads();
    }

    // ---- alpha = sigmoid( sum_d wa[d]*relu(attn[d]) + b ) ----
    const float4 wa   = *(const float4*)(w_alpha + 4 * tc);
    const float  bias = w_alpha_b[0];
#pragma unroll
    for (int i = 0; i < 4; ++i) {
        float p = fmaxf(acc2[i][0], 0.f) * wa.x + fmaxf(acc2[i][1], 0.f) * wa.y
                + fmaxf(acc2[i][2], 0.f) * wa.z + fmaxf(acc2[i][3], 0.f) * wa.w;
#pragma unroll
        for (int off = 1; off < 16; off <<= 1)
            p += __shfl_xor(p, off, 64);      // reduce over 16 tc lanes
        if (tc == 0) {
            const int e = e0 + 4 * tr + i;
            if (e < E) alpha_out[e] = 1.f / (1.f + __expf(-(p + bias)));
        }
    }
}

// ---------------------------------------------------------------------------
// Node kernel: per node, CSR-gather alpha_e*(hidden[sub]+rela[rel]+h_sub[e]),
// sum in registers (deterministic), then GEMM with folded WcT.
// LDS = 33.8K (A) + 16.9K (Wc slab) = 50.7 KB -> 3 blocks/CU.
// ---------------------------------------------------------------------------
__global__ __launch_bounds__(256, 3) void node_kernel(
    const float* __restrict__ hidden,
    const int*   __restrict__ edges,
    const float* __restrict__ h_sub,
    const float* __restrict__ rela,
    const float* __restrict__ alpha,
    const int*   __restrict__ start,
    const int*   __restrict__ deg,
    const int*   __restrict__ idx,
    const float* __restrict__ WcT,
    float* __restrict__ out,
    int N)
{
    __shared__ float A_s[BM * PAD_A];     // aggregated tile
    __shared__ float W_s[32 * PAD_W];     // WcT slab

    const int t  = threadIdx.x;
    const int n0 = blockIdx.x * BM;

    // ---- aggregate: 4 threads per node, 32 floats each ----
    {
        const int n_loc = t >> 2;
        const int seg   = t & 3;
        const int n     = n0 + n_loc;
        float4 acc8[8];
#pragma unroll
        for (int q = 0; q < 8; ++q) acc8[q] = make_float4(0.f, 0.f, 0.f, 0.f);
        if (n < N) {
            const int s0 = start[n];
            const int d0 = deg[n];
            for (int j = 0; j < d0; ++j) {
                const int   e   = idx[s0 + j];
                const float a   = alpha[e];
                const int   sub = edges[e * 6 + 4];
                const int   rel = edges[e * 6 + 2];
                const float4* hs = (const float4*)(hidden + (size_t)sub * 128 + seg * 32);
                const float4* hr = (const float4*)(rela   + (size_t)rel * 128 + seg * 32);
                const float4* hb = (const float4*)(h_sub  + (size_t)e   * 128 + seg * 32);
#pragma unroll
                for (int q = 0; q < 8; ++q) {
                    float4 x = hs[q], y = hr[q], z = hb[q];
                    acc8[q].x = fmaf(a, x.x + y.x + z.x, acc8[q].x);
                    acc8[q].y = fmaf(a, x.y + y.y + z.y, acc8[q].y);
                    acc8[q].z = fmaf(a, x.z + y.z + z.z, acc8[q].z);
                    acc8[q].w = fmaf(a, x.w + y.w + z.w, acc8[q].w);
                }
            }
        }
        float4* dst = (float4*)(A_s + n_loc * PAD_A + seg * 32);
#pragma unroll
        for (int q = 0; q < 8; ++q) dst[q] = acc8[q];
    }
    __syncthreads();

    const int tr = t >> 4;
    const int tc = t & 15;

    float acc[4][8];
#pragma unroll
    for (int i = 0; i < 4; ++i)
#pragma unroll
        for (int j = 0; j < 8; ++j) acc[i][j] = 0.f;

    for (int kk = 0; kk < 4; ++kk) {
        {   // stage WcT rows kk*32..+31 (128 cols) -> W_s, pad 132
            const int r  = t >> 3;          // 0..31
            const int c0 = (t & 7) * 16;    // 4 float4
            const float4* src = (const float4*)(WcT + (size_t)(kk * 32 + r) * 128 + c0);
            float4* dst = (float4*)(W_s + r * PAD_W + c0);
            dst[0] = src[0]; dst[1] = src[1]; dst[2] = src[2]; dst[3] = src[3];
        }
        __syncthreads();
#pragma unroll
        for (int k4 = 0; k4 < 8; ++k4) {
            float a[4][4];
#pragma unroll
            for (int i = 0; i < 4; ++i) {
                float4 v = *(const float4*)(A_s + (4 * tr + i) * PAD_A + kk * 32 + k4 * 4);
                a[i][0] = v.x; a[i][1] = v.y; a[i][2] = v.z; a[i][3] = v.w;
            }
            float4 b0[4], b1[4];
#pragma unroll
            for (int k = 0; k < 4; ++k) {
                const float* wrow = W_s + (k4 * 4 + k) * PAD_W + 8 * tc;
                b0[k] = *(const float4*)(wrow);
                b1[k] = *(const float4*)(wrow + 4);
            }
#pragma unroll
            for (int i = 0; i < 4; ++i)
#pragma unroll
                for (int k = 0; k < 4; ++k) {
                    const float av = a[i][k];
                    acc[i][0] = fmaf(av, b0[k].x, acc[i][0]);
                    acc[i][1] = fmaf(av, b0[k].y, acc[i][1]);
                    acc[i][2] = fmaf(av, b0[k].z, acc[i][2]);
                    acc[i][3] = fmaf(av, b0[k].w, acc[i][3]);
                    acc[i][4] = fmaf(av, b1[k].x, acc[i][4]);
                    acc[i][5] = fmaf(av, b1[k].y, acc[i][5]);
                    acc[i][6] = fmaf(av, b1[k].z, acc[i][6]);
                    acc[i][7] = fmaf(av, b1[k].w, acc[i][7]);
                }
        }
        __syncthreads();
    }

#pragma unroll
    for (int i = 0; i < 4; ++i) {
        const int n = n0 + 4 * tr + i;
        if (n >= N) continue;
        float4* dst = (float4*)(out + (size_t)n * 128 + 8 * tc);
        dst[0] = make_float4(acc[i][0], acc[i][1], acc[i][2], acc[i][3]);
        dst[1] = make_float4(acc[i][4], acc[i][5], acc[i][6], acc[i][7]);
    }
}

// ---------------------------------------------------------------------------
extern "C" void kernel_launch(void* const* d_in, const int* in_sizes, int n_in,
                              void* d_out, int out_size, void* d_ws, size_t ws_size,
                              hipStream_t stream)
{
    const float* hidden   = (const float*)d_in[1];
    const int*   edges    = (const int*)  d_in[2];
    const float* h_sub    = (const float*)d_in[6];
    const float* rela     = (const float*)d_in[7];
    const float* W1       = (const float*)d_in[8];
    const float* Ws       = (const float*)d_in[9];
    const float* w_alpha  = (const float*)d_in[11];
    const float* w_alphab = (const float*)d_in[12];
    const float* Wh       = (const float*)d_in[13];

    const int N = in_sizes[1] / 128;
    const int E = in_sizes[2] / 6;

    // ws layout (~3.8 MB)
    char* p = (char*)d_ws;
    float* WscT  = (float*)p;            p += (size_t)128 * 64  * 4;
    float* WcT   = (float*)p;            p += (size_t)128 * 128 * 4;
    int*   deg   = (int*)p;              p += (size_t)N * 4;
    int*   incl  = (int*)p;              p += (size_t)N * 4;
    int*   start = (int*)p;              p += (size_t)N * 4;
    int*   cursor= (int*)p;              p += (size_t)N * 4;
    int*   sums  = (int*)p;              p += 512 * 4;
    int*   offs  = (int*)p;              p += 512 * 4;
    int*   idx   = (int*)p;              p += (size_t)E * 4;

    float* out_hidden = (float*)d_out;                 // N*128
    float* out_alpha  = out_hidden + (size_t)N * 128;  // E

    const int NB = (N + 255) / 256;      // scan blocks (391)

    hipMemsetAsync(deg, 0, (size_t)N * 4, stream);
    fold_weights<<<96, 256, 0, stream>>>(W1, Ws, Wh, WscT, WcT);
    hist_kernel<<<(E + 255) / 256, 256, 0, stream>>>(edges, deg, E);
    scan1_kernel<<<NB, 256, 0, stream>>>(deg, incl, sums, N);
    scan2_kernel<<<1, 512, 0, stream>>>(sums, offs, NB);
    scan3_kernel<<<NB, 256, 0, stream>>>(incl, deg, offs, start, cursor, N);
    fill_kernel<<<(E + 255) / 256, 256, 0, stream>>>(edges, cursor, idx, E);

    edge_alpha_kernel<<<(E + BM - 1) / BM, 256, 0, stream>>>(
        hidden, edges, h_sub, rela, WscT, w_alpha, w_alphab, out_alpha, E);

    node_kernel<<<(N + BM - 1) / BM, 256, 0, stream>>>(
        hidden, edges, h_sub, rela, out_alpha, start, deg, idx, WcT,
        out_hidden, N);
}